// Round 1
// baseline (868.799 us; speedup 1.0000x reference)
//
#include <hip/hip_runtime.h>

// ---------------- problem constants (fixed by reference) ----------------
#define M_ROWS 131072      // B*N = 8*16384
#define DIM    256
#define T_CL   1024
#define HEADS  8
#define DH     32

typedef _Float16 f16;
typedef _Float16 f16x4 __attribute__((ext_vector_type(4)));
typedef _Float16 f16x8 __attribute__((ext_vector_type(8)));
typedef float    f32x4 __attribute__((ext_vector_type(4)));

#define INV2048 (1.0f/2048.0f)

// ---------------------------------------------------------------------------
// Kernel A/B1: row L2-normalize + split into f16 hi + f16 lo*2048.
// One wave per row (64 lanes x float4 = 256 elems).
// ---------------------------------------------------------------------------
__global__ __launch_bounds__(256) void norm_split_kernel(
    const float* __restrict__ src, f16* __restrict__ hi, f16* __restrict__ lo,
    int nrows)
{
  int lane = threadIdx.x & 63;
  int wid  = threadIdx.x >> 6;
  int row  = blockIdx.x * 4 + wid;
  if (row >= nrows) return;
  const float4 v = *(const float4*)&src[(size_t)row * DIM + lane * 4];
  float ss = v.x*v.x + v.y*v.y + v.z*v.z + v.w*v.w;
  #pragma unroll
  for (int off = 1; off < 64; off <<= 1) ss += __shfl_xor(ss, off);
  float rn = 1.0f / fmaxf(sqrtf(ss), 1e-12f);
  float n0 = v.x*rn, n1 = v.y*rn, n2 = v.z*rn, n3 = v.w*rn;
  f16 h0 = (f16)n0, h1 = (f16)n1, h2 = (f16)n2, h3 = (f16)n3;
  f16 l0 = (f16)((n0 - (float)h0) * 2048.0f);
  f16 l1 = (f16)((n1 - (float)h1) * 2048.0f);
  f16 l2 = (f16)((n2 - (float)h2) * 2048.0f);
  f16 l3 = (f16)((n3 - (float)h3) * 2048.0f);
  f16x4 hv = {h0, h1, h2, h3};
  f16x4 lv = {l0, l1, l2, l3};
  *(f16x4*)&hi[(size_t)row * DIM + lane * 4] = hv;
  *(f16x4*)&lo[(size_t)row * DIM + lane * 4] = lv;
}

// ---------------------------------------------------------------------------
// Kernel B2: dists GEMM (f16x2 split, 3 MFMA passes) + fused argmax over T.
// Block: 512 thr (8 waves, 2Mx4N), tile 128(M) x 128(N-chunk), BK=64.
// Loops all 8 N-chunks so the argmax stays in registers.
// LDS: A/B hi+lo tiles, XOR-swizzled via pre-swizzled global source.
// ---------------------------------------------------------------------------
#define BM 128
#define BN 128
#define BK 64

union SharedB2 {
  struct { f16 Ahi[BM][BK]; f16 Alo[BM][BK]; f16 Bhi[BN][BK]; f16 Blo[BN][BK]; } s; // 64 KB
  struct { float rv[4][BM]; int rc[4][BM]; } r;                                      // 4 KB
};

__global__ __launch_bounds__(512, 1) void dist_argmax_kernel(
    const f16* __restrict__ xhi, const f16* __restrict__ xlo,
    const f16* __restrict__ mhi, const f16* __restrict__ mlo,
    int* __restrict__ buckets, int* __restrict__ counts)
{
  __shared__ SharedB2 sh;
  const int tid  = threadIdx.x;
  const int lane = tid & 63;
  const int wid  = tid >> 6;
  const int wm   = wid >> 2;   // 0..1
  const int wn   = wid & 3;    // 0..3
  const int block_row0 = blockIdx.x * BM;

  // running per-lane argmax state: 16 row-slots (mf 0..3 x reg 0..3)
  float rbest[16];
  int   rcol[16];
  #pragma unroll
  for (int i = 0; i < 16; ++i) { rbest[i] = -1e30f; rcol[i] = 0; }

  for (int nc = 0; nc < T_CL / BN; ++nc) {
    f32x4 acc1[4][2], acc2[4][2];
    #pragma unroll
    for (int mf = 0; mf < 4; ++mf)
      #pragma unroll
      for (int nf = 0; nf < 2; ++nf) {
        f32x4 z = {0.f, 0.f, 0.f, 0.f};
        acc1[mf][nf] = z; acc2[mf][nf] = z;
      }

    for (int k0 = 0; k0 < DIM; k0 += BK) {
      // ---- stage A/B hi+lo tiles: global_load_lds, 16B/lane, swizzled src ----
      // dest is linear (wave-uniform base + lane*16); source chunk pre-XOR'd.
      #pragma unroll
      for (int s = 0; s < 2; ++s) {
        int reg = wid * 2 + s;              // 16 regions of 8 rows
        int r   = reg * 8 + (lane >> 3);    // tile row 0..127
        int cs  = (lane & 7) ^ (r & 7);     // swizzled 16B-chunk index
        size_t ga = (size_t)(block_row0 + r) * DIM + k0 + cs * 8;
        size_t gb = (size_t)(nc * BN + r)   * DIM + k0 + cs * 8;
        __builtin_amdgcn_global_load_lds(
            (const __attribute__((address_space(1))) void*)(xhi + ga),
            (__attribute__((address_space(3))) void*)&sh.s.Ahi[reg * 8][0], 16, 0, 0);
        __builtin_amdgcn_global_load_lds(
            (const __attribute__((address_space(1))) void*)(xlo + ga),
            (__attribute__((address_space(3))) void*)&sh.s.Alo[reg * 8][0], 16, 0, 0);
        __builtin_amdgcn_global_load_lds(
            (const __attribute__((address_space(1))) void*)(mhi + gb),
            (__attribute__((address_space(3))) void*)&sh.s.Bhi[reg * 8][0], 16, 0, 0);
        __builtin_amdgcn_global_load_lds(
            (const __attribute__((address_space(1))) void*)(mlo + gb),
            (__attribute__((address_space(3))) void*)&sh.s.Blo[reg * 8][0], 16, 0, 0);
      }
      __syncthreads();   // compiler drains vmcnt before barrier

      // ---- compute: 2 K=32 sub-steps, 3 MFMA per (mf,nf) ----
      #pragma unroll
      for (int ks = 0; ks < 2; ++ks) {
        f16x8 ah[4], al[4], bh[2], bl[2];
        #pragma unroll
        for (int mf = 0; mf < 4; ++mf) {
          int r  = wm * 64 + mf * 16 + (lane & 15);
          int cl = ks * 4 + (lane >> 4);          // linear chunk within BK
          int cw = cl ^ (r & 7);                  // swizzled
          ah[mf] = *(const f16x8*)&sh.s.Ahi[r][cw * 8];
          al[mf] = *(const f16x8*)&sh.s.Alo[r][cw * 8];
        }
        #pragma unroll
        for (int nf = 0; nf < 2; ++nf) {
          int r  = wn * 32 + nf * 16 + (lane & 15);
          int cl = ks * 4 + (lane >> 4);
          int cw = cl ^ (r & 7);
          bh[nf] = *(const f16x8*)&sh.s.Bhi[r][cw * 8];
          bl[nf] = *(const f16x8*)&sh.s.Blo[r][cw * 8];
        }
        #pragma unroll
        for (int mf = 0; mf < 4; ++mf)
          #pragma unroll
          for (int nf = 0; nf < 2; ++nf)
            acc1[mf][nf] = __builtin_amdgcn_mfma_f32_16x16x32_f16(ah[mf], bh[nf], acc1[mf][nf], 0, 0, 0);
        #pragma unroll
        for (int mf = 0; mf < 4; ++mf)
          #pragma unroll
          for (int nf = 0; nf < 2; ++nf)
            acc2[mf][nf] = __builtin_amdgcn_mfma_f32_16x16x32_f16(ah[mf], bl[nf], acc2[mf][nf], 0, 0, 0);
        #pragma unroll
        for (int mf = 0; mf < 4; ++mf)
          #pragma unroll
          for (int nf = 0; nf < 2; ++nf)
            acc2[mf][nf] = __builtin_amdgcn_mfma_f32_16x16x32_f16(al[mf], bh[nf], acc2[mf][nf], 0, 0, 0);
      }
      __syncthreads();   // protect LDS before next stage
    }

    // ---- epilogue: combine split accs, update running argmax ----
    // C layout (16x16): col = lane&15, row = (lane>>4)*4 + reg  [m89-verified]
    int c0 = nc * BN + wn * 32 + (lane & 15);
    #pragma unroll
    for (int mf = 0; mf < 4; ++mf)
      #pragma unroll
      for (int j = 0; j < 4; ++j) {
        float d0 = acc1[mf][0][j] + acc2[mf][0][j] * INV2048;
        float d1 = acc1[mf][1][j] + acc2[mf][1][j] * INV2048;
        float d; int cc;
        if (d1 > d0) { d = d1; cc = c0 + 16; } else { d = d0; cc = c0; }
        int ri = mf * 4 + j;
        // cols only increase across nc/nf -> strict > keeps lowest col on ties
        if (d > rbest[ri]) { rbest[ri] = d; rcol[ri] = cc; }
      }
  }

  // ---- reduce across the 16 lanes holding the same row (different cols) ----
  #pragma unroll
  for (int ri = 0; ri < 16; ++ri) {
    #pragma unroll
    for (int off = 1; off < 16; off <<= 1) {
      float ov = __shfl_xor(rbest[ri], off);
      int   oc = __shfl_xor(rcol[ri], off);
      if (ov > rbest[ri] || (ov == rbest[ri] && oc < rcol[ri])) {
        rbest[ri] = ov; rcol[ri] = oc;
      }
    }
  }
  // safe to reuse LDS: last k-loop iteration ended with __syncthreads
  if ((lane & 15) == 0) {
    #pragma unroll
    for (int mf = 0; mf < 4; ++mf)
      #pragma unroll
      for (int j = 0; j < 4; ++j) {
        int rloc = wm * 64 + mf * 16 + (lane >> 4) * 4 + j;
        sh.r.rv[wn][rloc] = rbest[mf * 4 + j];
        sh.r.rc[wn][rloc] = rcol[mf * 4 + j];
      }
  }
  __syncthreads();
  if (tid < BM) {
    float bv = sh.r.rv[0][tid]; int bc = sh.r.rc[0][tid];
    #pragma unroll
    for (int q = 1; q < 4; ++q) {
      float v = sh.r.rv[q][tid]; int c = sh.r.rc[q][tid];
      if (v > bv || (v == bv && c < bc)) { bv = v; bc = c; }
    }
    buckets[block_row0 + tid] = bc;
    atomicAdd(&counts[bc], 1);
  }
}

// ---------------------------------------------------------------------------
// Prefix over counts (1 block, 1024 threads)
// ---------------------------------------------------------------------------
__global__ __launch_bounds__(1024) void prefix_kernel(
    const int* __restrict__ counts, int* __restrict__ offsets, int* __restrict__ cursors)
{
  __shared__ int ws[16];
  int tid = threadIdx.x, lane = tid & 63, w = tid >> 6;
  int c = counts[tid];
  int s = c;
  #pragma unroll
  for (int off = 1; off < 64; off <<= 1) {
    int o = __shfl_up(s, off);
    if (lane >= off) s += o;
  }
  if (lane == 63) ws[w] = s;
  __syncthreads();
  if (w == 0 && lane < 16) {
    int t = ws[lane];
    #pragma unroll
    for (int off = 1; off < 16; off <<= 1) {
      int o = __shfl_up(t, off);
      if (lane >= off) t += o;
    }
    ws[lane] = t;
  }
  __syncthreads();
  int base = (w > 0) ? ws[w - 1] : 0;
  int incl = base + s;
  offsets[tid + 1] = incl;
  cursors[tid] = incl - c;
  if (tid == 0) offsets[0] = 0;
}

// ---------------------------------------------------------------------------
// Scatter row ids into per-bucket slots
// ---------------------------------------------------------------------------
__global__ __launch_bounds__(256) void scatter_kernel(
    const int* __restrict__ buckets, int* __restrict__ cursors, int* __restrict__ rowids)
{
  int i = blockIdx.x * 256 + threadIdx.x;
  if (i < M_ROWS) {
    int b = buckets[i];
    int p = atomicAdd(&cursors[b], 1);
    rowids[p] = i;
  }
}

// ---------------------------------------------------------------------------
// Per-bucket gather-reduce + l2norm; empty bucket -> keep normalized mean.
// 1 block per bucket, thread = dim.
// ---------------------------------------------------------------------------
__global__ __launch_bounds__(256) void reduce_kernel(
    const f16* __restrict__ xhi, const f16* __restrict__ xlo,
    const int* __restrict__ offsets, const int* __restrict__ rowids,
    const f16* __restrict__ mhi, const f16* __restrict__ mlo,
    float* __restrict__ xglobal)
{
  int t = blockIdx.x, tid = threadIdx.x;
  int beg = offsets[t], end = offsets[t + 1];
  float acc = 0.f;
  int o = beg;
  for (; o + 4 <= end; o += 4) {
    int r0 = rowids[o], r1 = rowids[o + 1], r2 = rowids[o + 2], r3 = rowids[o + 3];
    float v0 = (float)xhi[(size_t)r0 * DIM + tid] + (float)xlo[(size_t)r0 * DIM + tid] * INV2048;
    float v1 = (float)xhi[(size_t)r1 * DIM + tid] + (float)xlo[(size_t)r1 * DIM + tid] * INV2048;
    float v2 = (float)xhi[(size_t)r2 * DIM + tid] + (float)xlo[(size_t)r2 * DIM + tid] * INV2048;
    float v3 = (float)xhi[(size_t)r3 * DIM + tid] + (float)xlo[(size_t)r3 * DIM + tid] * INV2048;
    acc += v0; acc += v1; acc += v2; acc += v3;
  }
  for (; o < end; ++o) {
    int r = rowids[o];
    acc += (float)xhi[(size_t)r * DIM + tid] + (float)xlo[(size_t)r * DIM + tid] * INV2048;
  }
  // block-wide sum of squares
  float sq = acc * acc;
  #pragma unroll
  for (int off = 1; off < 64; off <<= 1) sq += __shfl_xor(sq, off);
  __shared__ float wsum[4];
  if ((tid & 63) == 0) wsum[tid >> 6] = sq;
  __syncthreads();
  float tot = wsum[0] + wsum[1] + wsum[2] + wsum[3];
  float rn = 1.0f / fmaxf(sqrtf(tot), 1e-12f);
  float outv;
  if (end > beg) outv = acc * rn;
  else outv = (float)mhi[(size_t)t * DIM + tid] + (float)mlo[(size_t)t * DIM + tid] * INV2048;
  xglobal[(size_t)t * DIM + tid] = outv;
}

// ---------------------------------------------------------------------------
// k/v projections: k[h,t,d] = sum_dd xg[t][dd] * Wk[h*32+d][dd]  (fp32)
// Block: 8 t-rows x 256 output features; W staged in LDS chunks (coalesced).
// ---------------------------------------------------------------------------
#define TB 8
__global__ __launch_bounds__(256) void kv_kernel(
    const float* __restrict__ xg_in, const float* __restrict__ Wk,
    const float* __restrict__ Wv, float* __restrict__ out)
{
  __shared__ float xg[TB][DIM];     // 8 KB
  __shared__ float Wc[DIM][33];     // 33.8 KB (pad 33 -> conflict-free reads)
  int tid = threadIdx.x;
  int t0 = blockIdx.x * TB;
  for (int i = tid; i < TB * DIM; i += 256) xg[i >> 8][i & 255] = xg_in[(size_t)t0 * DIM + i];
  float acck[TB], accv[TB];
  #pragma unroll
  for (int tt = 0; tt < TB; ++tt) { acck[tt] = 0.f; accv[tt] = 0.f; }

  for (int c = 0; c < DIM; c += 32) {
    __syncthreads();
    for (int i = tid; i < DIM * 8; i += 256) {      // 2048 float4 granules
      int j = i >> 3, d4 = i & 7;
      float4 wv4 = *(const float4*)&Wk[(size_t)j * DIM + c + d4 * 4];
      Wc[j][d4 * 4 + 0] = wv4.x; Wc[j][d4 * 4 + 1] = wv4.y;
      Wc[j][d4 * 4 + 2] = wv4.z; Wc[j][d4 * 4 + 3] = wv4.w;
    }
    __syncthreads();
    #pragma unroll 8
    for (int dd = 0; dd < 32; ++dd) {
      float w = Wc[tid][dd];
      #pragma unroll
      for (int tt = 0; tt < TB; ++tt) acck[tt] = fmaf(w, xg[tt][c + dd], acck[tt]);
    }
  }
  for (int c = 0; c < DIM; c += 32) {
    __syncthreads();
    for (int i = tid; i < DIM * 8; i += 256) {
      int j = i >> 3, d4 = i & 7;
      float4 wv4 = *(const float4*)&Wv[(size_t)j * DIM + c + d4 * 4];
      Wc[j][d4 * 4 + 0] = wv4.x; Wc[j][d4 * 4 + 1] = wv4.y;
      Wc[j][d4 * 4 + 2] = wv4.z; Wc[j][d4 * 4 + 3] = wv4.w;
    }
    __syncthreads();
    #pragma unroll 8
    for (int dd = 0; dd < 32; ++dd) {
      float w = Wc[tid][dd];
      #pragma unroll
      for (int tt = 0; tt < TB; ++tt) accv[tt] = fmaf(w, xg[tt][c + dd], accv[tt]);
    }
  }
  int h = tid >> 5, d = tid & 31;
  #pragma unroll
  for (int tt = 0; tt < TB; ++tt) {
    out[(size_t)h * (T_CL * DH) + (size_t)(t0 + tt) * DH + d] = acck[tt];
    out[262144 + (size_t)h * (T_CL * DH) + (size_t)(t0 + tt) * DH + d] = accv[tt];
  }
}

// ---------------------------------------------------------------------------
extern "C" void kernel_launch(void* const* d_in, const int* in_sizes, int n_in,
                              void* d_out, int out_size, void* d_ws, size_t ws_size,
                              hipStream_t stream)
{
  const float* normed_x = (const float*)d_in[0];   // [8,16384,256]
  const float* x_means  = (const float*)d_in[1];   // [1024,256]
  const float* Wk       = (const float*)d_in[2];   // [256,256]
  const float* Wv       = (const float*)d_in[3];   // [256,256]
  float* out = (float*)d_out;                      // k|v|x_global = 786432 f32

  char* w = (char*)d_ws;
  f16* xhi     = (f16*)(w);                        // 67108864 B
  f16* xlo     = (f16*)(w + 67108864);             // 67108864 B
  f16* mhi     = (f16*)(w + 134217728);            // 524288 B
  f16* mlo     = (f16*)(w + 134742016);            // 524288 B
  int* buckets = (int*)(w + 135266304);            // 524288 B
  int* counts  = (int*)(w + 135790592);            // 4096 B
  int* offsets = (int*)(w + 135794688);            // 4352 B
  int* cursors = (int*)(w + 135799040);            // 4096 B
  int* rowids  = (int*)(w + 135803136);            // 524288 B  (total ~136.3 MB)

  hipMemsetAsync(counts, 0, T_CL * sizeof(int), stream);

  hipLaunchKernelGGL(norm_split_kernel, dim3(T_CL / 4), dim3(256), 0, stream,
                     x_means, mhi, mlo, T_CL);
  hipLaunchKernelGGL(norm_split_kernel, dim3(M_ROWS / 4), dim3(256), 0, stream,
                     normed_x, xhi, xlo, M_ROWS);
  hipLaunchKernelGGL(dist_argmax_kernel, dim3(M_ROWS / BM), dim3(512), 0, stream,
                     xhi, xlo, mhi, mlo, buckets, counts);
  hipLaunchKernelGGL(prefix_kernel, dim3(1), dim3(1024), 0, stream,
                     counts, offsets, cursors);
  hipLaunchKernelGGL(scatter_kernel, dim3(M_ROWS / 256), dim3(256), 0, stream,
                     buckets, cursors, rowids);
  hipLaunchKernelGGL(reduce_kernel, dim3(T_CL), dim3(256), 0, stream,
                     xhi, xlo, offsets, rowids, mhi, mlo, out + 524288);
  hipLaunchKernelGGL(kv_kernel, dim3(T_CL / TB), dim3(256), 0, stream,
                     out + 524288, Wk, Wv, out);
}

// Round 2
// 815.007 us; speedup vs baseline: 1.0660x; 1.0660x over previous
//
#include <hip/hip_runtime.h>

// ---------------- problem constants (fixed by reference) ----------------
#define M_ROWS 131072      // B*N = 8*16384
#define DIM    256
#define T_CL   1024
#define HEADS  8
#define DH     32

typedef _Float16 f16;
typedef _Float16 f16x4 __attribute__((ext_vector_type(4)));
typedef _Float16 f16x8 __attribute__((ext_vector_type(8)));
typedef float    f32x16 __attribute__((ext_vector_type(16)));

#define INV2048 (1.0f/2048.0f)

// ---------------------------------------------------------------------------
// Kernel 1: row L2-normalize + split into f16 hi + f16 lo*2048.
// One wave per row (64 lanes x float4 = 256 elems).
// ---------------------------------------------------------------------------
__global__ __launch_bounds__(256) void norm_split_kernel(
    const float* __restrict__ src, f16* __restrict__ hi, f16* __restrict__ lo,
    int nrows)
{
  int lane = threadIdx.x & 63;
  int wid  = threadIdx.x >> 6;
  int row  = blockIdx.x * 4 + wid;
  if (row >= nrows) return;
  const float4 v = *(const float4*)&src[(size_t)row * DIM + lane * 4];
  float ss = v.x*v.x + v.y*v.y + v.z*v.z + v.w*v.w;
  #pragma unroll
  for (int off = 1; off < 64; off <<= 1) ss += __shfl_xor(ss, off);
  float rn = 1.0f / fmaxf(sqrtf(ss), 1e-12f);
  float n0 = v.x*rn, n1 = v.y*rn, n2 = v.z*rn, n3 = v.w*rn;
  f16 h0 = (f16)n0, h1 = (f16)n1, h2 = (f16)n2, h3 = (f16)n3;
  f16 l0 = (f16)((n0 - (float)h0) * 2048.0f);
  f16 l1 = (f16)((n1 - (float)h1) * 2048.0f);
  f16 l2 = (f16)((n2 - (float)h2) * 2048.0f);
  f16 l3 = (f16)((n3 - (float)h3) * 2048.0f);
  f16x4 hv = {h0, h1, h2, h3};
  f16x4 lv = {l0, l1, l2, l3};
  *(f16x4*)&hi[(size_t)row * DIM + lane * 4] = hv;
  *(f16x4*)&lo[(size_t)row * DIM + lane * 4] = lv;
}

// ---------------------------------------------------------------------------
// Kernel 2: dists GEMM (f16-split, 3 MFMA passes, 32x32x16) + per-nc argmax
// candidates to global.
// Block: 512 thr (8 waves as 2M x 4N), tile BM=128 x BN=256, BK=32.
// LDS rows = 128 B (32 hi f16 | 32 lo f16), 3-bit XOR chunk swizzle,
// staged via global_load_lds with pre-swizzled per-lane global source.
// 2-phase pipeline: stage(t+1) issued before compute(t); one barrier/step.
// ---------------------------------------------------------------------------
#define BM 128
#define BN 256
#define BK 32
#define NSTEP 32   // 4 nc x 8 k-steps

__global__ __launch_bounds__(512, 2) void dist_argmax_kernel(
    const f16* __restrict__ xhi, const f16* __restrict__ xlo,
    const f16* __restrict__ mhi, const f16* __restrict__ mlo,
    float2* __restrict__ cand)
{
  // [buf][row][64 f16 = 4 hi-chunks | 4 lo-chunks, chunk-swizzled]
  __shared__ alignas(16) f16 ldsA[2][BM][64];   // 32 KB
  __shared__ alignas(16) f16 ldsB[2][BN][64];   // 64 KB

  const int tid  = threadIdx.x;
  const int lane = tid & 63;
  const int wid  = tid >> 6;          // 0..7
  const int wm   = wid >> 2;          // 0..1  (row half)
  const int wn   = wid & 3;           // 0..3  (col quarter)
  const size_t brow0 = (size_t)blockIdx.x * BM;

  // ---- staging per-lane constants (constant across steps) ----
  const int srow = lane >> 3;                 // 0..7 row within 8-row group
  const int cl   = (lane & 7) ^ srow;         // logical chunk this lane carries
  const f16* baseA = (cl < 4) ? xhi : xlo;
  const f16* baseB = (cl < 4) ? mhi : mlo;
  const size_t lofs = (size_t)srow * DIM + (size_t)(cl & 3) * 8;

  // ---- fragment-read per-lane constants ----
  const int half = lane >> 5;                 // k-half within K=16 step
  const int l31  = lane & 31;
  int raRow[2], rbRow[4 == 4 ? 2 : 2];
  #pragma unroll
  for (int mf = 0; mf < 2; ++mf) raRow[mf] = wm * 64 + mf * 32 + l31;
  int rbR[2];
  #pragma unroll
  for (int nf = 0; nf < 2; ++nf) rbR[nf] = wn * 64 + nf * 32 + l31;

  f32x16 acc1[2][2], acc2[2][2];
  #pragma unroll
  for (int mf = 0; mf < 2; ++mf)
    #pragma unroll
    for (int nf = 0; nf < 2; ++nf)
      #pragma unroll
      for (int r = 0; r < 16; ++r) { acc1[mf][nf][r] = 0.f; acc2[mf][nf][r] = 0.f; }

#define GLL(SRC, DST) __builtin_amdgcn_global_load_lds( \
    (const __attribute__((address_space(1))) void*)(SRC), \
    (__attribute__((address_space(3))) void*)(DST), 16, 0, 0)

#define STAGE(V, BUF) { \
    int nc_ = (V) >> 3; int k0_ = ((V) & 7) * BK; \
    _Pragma("unroll") \
    for (int j = 0; j < 2; ++j) { \
      int r0 = wid * 16 + j * 8; \
      const f16* s = baseA + lofs + (brow0 + r0) * DIM + k0_; \
      GLL(s, &ldsA[BUF][r0][0]); \
    } \
    _Pragma("unroll") \
    for (int j = 0; j < 4; ++j) { \
      int r0 = wid * 32 + j * 8; \
      const f16* s = baseB + lofs + (size_t)(nc_ * BN + r0) * DIM + k0_; \
      GLL(s, &ldsB[BUF][r0][0]); \
    } }

  // ---- prologue ----
  STAGE(0, 0);
  __syncthreads();

  #pragma unroll 1
  for (int t = 0; t < NSTEP; ++t) {
    const int buf = t & 1;
    if (t < NSTEP - 1) STAGE(t + 1, buf ^ 1);

    // ---- compute step t from ldsX[buf]: 2 K=16 sub-steps ----
    const char* Ab = (const char*)&ldsA[buf][0][0];
    const char* Bb = (const char*)&ldsB[buf][0][0];
    #pragma unroll
    for (int ks = 0; ks < 2; ++ks) {
      f16x8 ah[2], al[2], bh[2], bl[2];
      const int clh = ks * 2 + half;                 // hi logical chunk 0..3
      #pragma unroll
      for (int mf = 0; mf < 2; ++mf) {
        int off = raRow[mf] * 128 + ((clh ^ (raRow[mf] & 7)) * 16);
        ah[mf] = *(const f16x8*)(Ab + off);
        al[mf] = *(const f16x8*)(Ab + (off ^ 64));   // lo chunk = hi chunk ^ 4
      }
      #pragma unroll
      for (int nf = 0; nf < 2; ++nf) {
        int off = rbR[nf] * 128 + ((clh ^ (rbR[nf] & 7)) * 16);
        bh[nf] = *(const f16x8*)(Bb + off);
        bl[nf] = *(const f16x8*)(Bb + (off ^ 64));
      }
      #pragma unroll
      for (int mf = 0; mf < 2; ++mf)
        #pragma unroll
        for (int nf = 0; nf < 2; ++nf)
          acc1[mf][nf] = __builtin_amdgcn_mfma_f32_32x32x16_f16(ah[mf], bh[nf], acc1[mf][nf], 0, 0, 0);
      #pragma unroll
      for (int mf = 0; mf < 2; ++mf)
        #pragma unroll
        for (int nf = 0; nf < 2; ++nf) {
          acc2[mf][nf] = __builtin_amdgcn_mfma_f32_32x32x16_f16(ah[mf], bl[nf], acc2[mf][nf], 0, 0, 0);
          acc2[mf][nf] = __builtin_amdgcn_mfma_f32_32x32x16_f16(al[mf], bh[nf], acc2[mf][nf], 0, 0, 0);
        }
    }

    // ---- per-nc epilogue: local argmax -> global candidates ----
    if ((t & 7) == 7) {
      const int nc = t >> 3;
      const int cbase = nc * BN + wn * 64 + l31;
      #pragma unroll
      for (int mf = 0; mf < 2; ++mf) {
        #pragma unroll
        for (int rg = 0; rg < 16; ++rg) {
          float d0 = acc1[mf][0][rg] + acc2[mf][0][rg] * INV2048;
          float d1 = acc1[mf][1][rg] + acc2[mf][1][rg] * INV2048;
          float dv = d0; int dc = cbase;
          if (d1 > d0) { dv = d1; dc = cbase + 32; }   // tie -> lower col
          #pragma unroll
          for (int off = 1; off < 32; off <<= 1) {
            float ov = __shfl_xor(dv, off);
            int   oc = __shfl_xor(dc, off);
            if (ov > dv || (ov == dv && oc < dc)) { dv = ov; dc = oc; }
          }
          if (l31 == 0) {
            int rloc = wm * 64 + mf * 32 + (rg & 3) + 8 * (rg >> 2) + 4 * half;
            cand[(brow0 + rloc) * 16 + nc * 4 + wn] = make_float2(dv, __int_as_float(dc));
          }
        }
        #pragma unroll
        for (int nf = 0; nf < 2; ++nf)
          #pragma unroll
          for (int r = 0; r < 16; ++r) { acc1[mf][nf][r] = 0.f; acc2[mf][nf][r] = 0.f; }
      }
    }
    __syncthreads();
  }
#undef STAGE
#undef GLL
}

// ---------------------------------------------------------------------------
// Kernel 3: merge 16 candidates per row -> bucket + counts
// ---------------------------------------------------------------------------
__global__ __launch_bounds__(256) void merge_kernel(
    const float2* __restrict__ cand, int* __restrict__ buckets, int* __restrict__ counts)
{
  int row = blockIdx.x * 256 + threadIdx.x;
  float bv = -1e30f; int bc = 0;
  #pragma unroll
  for (int s = 0; s < 16; ++s) {
    float2 c = cand[(size_t)row * 16 + s];
    int cc = __float_as_int(c.y);
    if (c.x > bv || (c.x == bv && cc < bc)) { bv = c.x; bc = cc; }
  }
  buckets[row] = bc;
  atomicAdd(&counts[bc], 1);
}

// ---------------------------------------------------------------------------
// Prefix over counts (1 block, 1024 threads)
// ---------------------------------------------------------------------------
__global__ __launch_bounds__(1024) void prefix_kernel(
    const int* __restrict__ counts, int* __restrict__ offsets, int* __restrict__ cursors)
{
  __shared__ int ws[16];
  int tid = threadIdx.x, lane = tid & 63, w = tid >> 6;
  int c = counts[tid];
  int s = c;
  #pragma unroll
  for (int off = 1; off < 64; off <<= 1) {
    int o = __shfl_up(s, off);
    if (lane >= off) s += o;
  }
  if (lane == 63) ws[w] = s;
  __syncthreads();
  if (w == 0 && lane < 16) {
    int t = ws[lane];
    #pragma unroll
    for (int off = 1; off < 16; off <<= 1) {
      int o = __shfl_up(t, off);
      if (lane >= off) t += o;
    }
    ws[lane] = t;
  }
  __syncthreads();
  int base = (w > 0) ? ws[w - 1] : 0;
  int incl = base + s;
  offsets[tid + 1] = incl;
  cursors[tid] = incl - c;
  if (tid == 0) offsets[0] = 0;
}

// ---------------------------------------------------------------------------
// Scatter row ids into per-bucket slots
// ---------------------------------------------------------------------------
__global__ __launch_bounds__(256) void scatter_kernel(
    const int* __restrict__ buckets, int* __restrict__ cursors, int* __restrict__ rowids)
{
  int i = blockIdx.x * 256 + threadIdx.x;
  if (i < M_ROWS) {
    int b = buckets[i];
    int p = atomicAdd(&cursors[b], 1);
    rowids[p] = i;
  }
}

// ---------------------------------------------------------------------------
// Per-bucket gather-reduce + l2norm; empty bucket -> keep normalized mean.
// 1 block per bucket, thread = dim.
// ---------------------------------------------------------------------------
__global__ __launch_bounds__(256) void reduce_kernel(
    const f16* __restrict__ xhi, const f16* __restrict__ xlo,
    const int* __restrict__ offsets, const int* __restrict__ rowids,
    const f16* __restrict__ mhi, const f16* __restrict__ mlo,
    float* __restrict__ xglobal)
{
  int t = blockIdx.x, tid = threadIdx.x;
  int beg = offsets[t], end = offsets[t + 1];
  float acc = 0.f;
  int o = beg;
  for (; o + 4 <= end; o += 4) {
    int r0 = rowids[o], r1 = rowids[o + 1], r2 = rowids[o + 2], r3 = rowids[o + 3];
    float v0 = (float)xhi[(size_t)r0 * DIM + tid] + (float)xlo[(size_t)r0 * DIM + tid] * INV2048;
    float v1 = (float)xhi[(size_t)r1 * DIM + tid] + (float)xlo[(size_t)r1 * DIM + tid] * INV2048;
    float v2 = (float)xhi[(size_t)r2 * DIM + tid] + (float)xlo[(size_t)r2 * DIM + tid] * INV2048;
    float v3 = (float)xhi[(size_t)r3 * DIM + tid] + (float)xlo[(size_t)r3 * DIM + tid] * INV2048;
    acc += v0; acc += v1; acc += v2; acc += v3;
  }
  for (; o < end; ++o) {
    int r = rowids[o];
    acc += (float)xhi[(size_t)r * DIM + tid] + (float)xlo[(size_t)r * DIM + tid] * INV2048;
  }
  float sq = acc * acc;
  #pragma unroll
  for (int off = 1; off < 64; off <<= 1) sq += __shfl_xor(sq, off);
  __shared__ float wsum[4];
  if ((tid & 63) == 0) wsum[tid >> 6] = sq;
  __syncthreads();
  float tot = wsum[0] + wsum[1] + wsum[2] + wsum[3];
  float rn = 1.0f / fmaxf(sqrtf(tot), 1e-12f);
  float outv;
  if (end > beg) outv = acc * rn;
  else outv = (float)mhi[(size_t)t * DIM + tid] + (float)mlo[(size_t)t * DIM + tid] * INV2048;
  xglobal[(size_t)t * DIM + tid] = outv;
}

// ---------------------------------------------------------------------------
// k/v projections (fp32 vector; tiny)
// ---------------------------------------------------------------------------
#define TB 8
__global__ __launch_bounds__(256) void kv_kernel(
    const float* __restrict__ xg_in, const float* __restrict__ Wk,
    const float* __restrict__ Wv, float* __restrict__ out)
{
  __shared__ float xg[TB][DIM];     // 8 KB
  __shared__ float Wc[DIM][33];     // 33.8 KB
  int tid = threadIdx.x;
  int t0 = blockIdx.x * TB;
  for (int i = tid; i < TB * DIM; i += 256) xg[i >> 8][i & 255] = xg_in[(size_t)t0 * DIM + i];
  float acck[TB], accv[TB];
  #pragma unroll
  for (int tt = 0; tt < TB; ++tt) { acck[tt] = 0.f; accv[tt] = 0.f; }

  for (int c = 0; c < DIM; c += 32) {
    __syncthreads();
    for (int i = tid; i < DIM * 8; i += 256) {
      int j = i >> 3, d4 = i & 7;
      float4 wv4 = *(const float4*)&Wk[(size_t)j * DIM + c + d4 * 4];
      Wc[j][d4 * 4 + 0] = wv4.x; Wc[j][d4 * 4 + 1] = wv4.y;
      Wc[j][d4 * 4 + 2] = wv4.z; Wc[j][d4 * 4 + 3] = wv4.w;
    }
    __syncthreads();
    #pragma unroll 8
    for (int dd = 0; dd < 32; ++dd) {
      float w = Wc[tid][dd];
      #pragma unroll
      for (int tt = 0; tt < TB; ++tt) acck[tt] = fmaf(w, xg[tt][c + dd], acck[tt]);
    }
  }
  for (int c = 0; c < DIM; c += 32) {
    __syncthreads();
    for (int i = tid; i < DIM * 8; i += 256) {
      int j = i >> 3, d4 = i & 7;
      float4 wv4 = *(const float4*)&Wv[(size_t)j * DIM + c + d4 * 4];
      Wc[j][d4 * 4 + 0] = wv4.x; Wc[j][d4 * 4 + 1] = wv4.y;
      Wc[j][d4 * 4 + 2] = wv4.z; Wc[j][d4 * 4 + 3] = wv4.w;
    }
    __syncthreads();
    #pragma unroll 8
    for (int dd = 0; dd < 32; ++dd) {
      float w = Wc[tid][dd];
      #pragma unroll
      for (int tt = 0; tt < TB; ++tt) accv[tt] = fmaf(w, xg[tt][c + dd], accv[tt]);
    }
  }
  int h = tid >> 5, d = tid & 31;
  #pragma unroll
  for (int tt = 0; tt < TB; ++tt) {
    out[(size_t)h * (T_CL * DH) + (size_t)(t0 + tt) * DH + d] = acck[tt];
    out[262144 + (size_t)h * (T_CL * DH) + (size_t)(t0 + tt) * DH + d] = accv[tt];
  }
}

// ---------------------------------------------------------------------------
extern "C" void kernel_launch(void* const* d_in, const int* in_sizes, int n_in,
                              void* d_out, int out_size, void* d_ws, size_t ws_size,
                              hipStream_t stream)
{
  const float* normed_x = (const float*)d_in[0];   // [8,16384,256]
  const float* x_means  = (const float*)d_in[1];   // [1024,256]
  const float* Wk       = (const float*)d_in[2];   // [256,256]
  const float* Wv       = (const float*)d_in[3];   // [256,256]
  float* out = (float*)d_out;                      // k|v|x_global = 786432 f32

  char* w = (char*)d_ws;
  f16*    xhi     = (f16*)(w);                     // 67108864 B
  f16*    xlo     = (f16*)(w + 67108864);          // 67108864 B
  f16*    mhi     = (f16*)(w + 134217728);         // 524288 B
  f16*    mlo     = (f16*)(w + 134742016);         // 524288 B
  float2* cand    = (float2*)(w + 135266304);      // 16777216 B
  int*    buckets = (int*)(w + 152043520);         // 524288 B
  int*    counts  = (int*)(w + 152567808);         // 4096 B
  int*    offsets = (int*)(w + 152571904);         // 4352 B
  int*    cursors = (int*)(w + 152576256);         // 4096 B
  int*    rowids  = (int*)(w + 152580352);         // 524288 B (end ~153.1 MB)

  hipMemsetAsync(counts, 0, T_CL * sizeof(int), stream);

  hipLaunchKernelGGL(norm_split_kernel, dim3(T_CL / 4), dim3(256), 0, stream,
                     x_means, mhi, mlo, T_CL);
  hipLaunchKernelGGL(norm_split_kernel, dim3(M_ROWS / 4), dim3(256), 0, stream,
                     normed_x, xhi, xlo, M_ROWS);
  hipLaunchKernelGGL(dist_argmax_kernel, dim3(M_ROWS / BM), dim3(512), 0, stream,
                     xhi, xlo, mhi, mlo, cand);
  hipLaunchKernelGGL(merge_kernel, dim3(M_ROWS / 256), dim3(256), 0, stream,
                     cand, buckets, counts);
  hipLaunchKernelGGL(prefix_kernel, dim3(1), dim3(1024), 0, stream,
                     counts, offsets, cursors);
  hipLaunchKernelGGL(scatter_kernel, dim3(M_ROWS / 256), dim3(256), 0, stream,
                     buckets, cursors, rowids);
  hipLaunchKernelGGL(reduce_kernel, dim3(T_CL), dim3(256), 0, stream,
                     xhi, xlo, offsets, rowids, mhi, mlo, out + 524288);
  hipLaunchKernelGGL(kv_kernel, dim3(T_CL / TB), dim3(256), 0, stream,
                     out + 524288, Wk, Wv, out);
}

// Round 3
// 807.950 us; speedup vs baseline: 1.0753x; 1.0087x over previous
//
#include <hip/hip_runtime.h>

// ---------------- problem constants (fixed by reference) ----------------
#define M_ROWS 131072      // B*N = 8*16384
#define DIM    256
#define T_CL   1024
#define HEADS  8
#define DH     32

typedef _Float16 f16;
typedef _Float16 f16x2 __attribute__((ext_vector_type(2)));
typedef _Float16 f16x4 __attribute__((ext_vector_type(4)));
typedef _Float16 f16x8 __attribute__((ext_vector_type(8)));
typedef float    f32x16 __attribute__((ext_vector_type(16)));

#define INV2048 (1.0f/2048.0f)

// Packed row layout ("pk"): per row, 32 chunk-pairs; chunk c = elements
// 8c..8c+7: [hi c (16B)][lo c (16B)] -> row = 1024 B = 64 16-B slots.
// Linear slot g: hi of chunk c at g=2c, lo at g=2c+1.

// ---------------------------------------------------------------------------
// Kernel 1: row L2-normalize + split into f16 hi + f16 lo*2048, packed layout.
// One wave per row (64 lanes x float4 = 256 elems).
// ---------------------------------------------------------------------------
__global__ __launch_bounds__(256) void norm_split_kernel(
    const float* __restrict__ src, f16* __restrict__ pk, int nrows)
{
  int lane = threadIdx.x & 63;
  int wid  = threadIdx.x >> 6;
  int row  = blockIdx.x * 4 + wid;
  if (row >= nrows) return;
  const float4 v = *(const float4*)&src[(size_t)row * DIM + lane * 4];
  float ss = v.x*v.x + v.y*v.y + v.z*v.z + v.w*v.w;
  #pragma unroll
  for (int off = 1; off < 64; off <<= 1) ss += __shfl_xor(ss, off);
  float rn = 1.0f / fmaxf(sqrtf(ss), 1e-12f);
  float n0 = v.x*rn, n1 = v.y*rn, n2 = v.z*rn, n3 = v.w*rn;
  f16 h0 = (f16)n0, h1 = (f16)n1, h2 = (f16)n2, h3 = (f16)n3;
  f16 l0 = (f16)((n0 - (float)h0) * 2048.0f);
  f16 l1 = (f16)((n1 - (float)h1) * 2048.0f);
  f16 l2 = (f16)((n2 - (float)h2) * 2048.0f);
  f16 l3 = (f16)((n3 - (float)h3) * 2048.0f);
  f16x4 hv = {h0, h1, h2, h3};
  f16x4 lv = {l0, l1, l2, l3};
  // elems lane*4..+3: chunk c = lane>>1, half-of-chunk = lane&1
  char* base = (char*)pk + (size_t)row * 1024 + (lane >> 1) * 32 + (lane & 1) * 8;
  *(f16x4*)base        = hv;
  *(f16x4*)(base + 16) = lv;
}

// ---------------------------------------------------------------------------
// Kernel 2: dists GEMM (f16-split, 3 MFMA passes, 32x32x16) + per-nc argmax.
// A (x rows) resident in LDS full-K (128 KB, staged once, XOR-slot swizzle);
// B (means) fragments loaded global->VGPR (L2-hot), double-buffered.
// NO barriers in the main loop: waves free-run.
// ---------------------------------------------------------------------------
#define MFMA16(A,B,C) __builtin_amdgcn_mfma_f32_32x32x16_f16(A,B,C,0,0,0)

#define AFRAG(KS, AH0, AH1, AL0, AL1) { \
  const int gg = 4*(KS) + 2*half; \
  const int hs = gg ^ l31; \
  AH0 = *(const f16x8*)(Ab + rb0 + hs*16); \
  AL0 = *(const f16x8*)(Ab + rb0 + (hs^1)*16); \
  AH1 = *(const f16x8*)(Ab + rb1 + hs*16); \
  AL1 = *(const f16x8*)(Ab + rb1 + (hs^1)*16); }

#define DOMFMA(AH0, AH1, AL0, AL1, BH0, BH1, BL0, BL1) \
  acc1[0][0] = MFMA16(AH0, BH0, acc1[0][0]); \
  acc1[1][0] = MFMA16(AH1, BH0, acc1[1][0]); \
  acc1[0][1] = MFMA16(AH0, BH1, acc1[0][1]); \
  acc1[1][1] = MFMA16(AH1, BH1, acc1[1][1]); \
  acc2[0][0] = MFMA16(AH0, BL0, acc2[0][0]); \
  acc2[1][0] = MFMA16(AH1, BL0, acc2[1][0]); \
  acc2[0][1] = MFMA16(AH0, BL1, acc2[0][1]); \
  acc2[1][1] = MFMA16(AH1, BL1, acc2[1][1]); \
  acc2[0][0] = MFMA16(AL0, BH0, acc2[0][0]); \
  acc2[1][0] = MFMA16(AL1, BH0, acc2[1][0]); \
  acc2[0][1] = MFMA16(AL0, BH1, acc2[0][1]); \
  acc2[1][1] = MFMA16(AL1, BH1, acc2[1][1]);

__global__ __launch_bounds__(512, 2) void dist_argmax_kernel(
    const f16* __restrict__ xpk, const f16* __restrict__ mpk,
    float2* __restrict__ cand)
{
  __shared__ alignas(16) f16 ldsA[128][512];   // 128 KB

  const int tid  = threadIdx.x;
  const int lane = tid & 63;
  const int wid  = tid >> 6;          // 0..7
  const int wm   = wid >> 2;          // 0..1
  const int wn   = wid & 3;           // 0..3
  const int l31  = lane & 31;
  const int half = lane >> 5;
  const size_t brow0 = (size_t)blockIdx.x * 128;

  // ---- stage A once: one GLL per row (1024 B), swizzled source slots ----
  #pragma unroll
  for (int it = 0; it < 16; ++it) {
    int r = wid * 16 + it;
    const f16* src = xpk + (brow0 + r) * 512 + ((lane ^ (r & 31)) * 8);
    __builtin_amdgcn_global_load_lds(
        (const __attribute__((address_space(1))) void*)src,
        (__attribute__((address_space(3))) void*)&ldsA[r][0], 16, 0, 0);
  }
  __syncthreads();

  const char* Ab = (const char*)&ldsA[0][0];
  const int rA0 = wm * 64 + l31;            // (rA0&31)==(rA1&31)==l31
  const int rA1 = rA0 + 32;
  const size_t rb0 = (size_t)rA0 * 1024;
  const size_t rb1 = (size_t)rA1 * 1024;

  const f16* bb0 = mpk + (size_t)(wn * 64 + 0  + l31) * 512 + half * 16;
  const f16* bb1 = mpk + (size_t)(wn * 64 + 32 + l31) * 512 + half * 16;

  #pragma unroll 1
  for (int nc = 0; nc < 4; ++nc) {
    const f16* __restrict__ b0 = bb0 + nc * 131072;   // 256 rows * 512 f16
    const f16* __restrict__ b1 = bb1 + nc * 131072;

    f32x16 acc1[2][2], acc2[2][2];
    #pragma unroll
    for (int mf = 0; mf < 2; ++mf)
      #pragma unroll
      for (int nf = 0; nf < 2; ++nf)
        #pragma unroll
        for (int r = 0; r < 16; ++r) { acc1[mf][nf][r] = 0.f; acc2[mf][nf][r] = 0.f; }

    f16x8 h0A = *(const f16x8*)(b0);
    f16x8 l0A = *(const f16x8*)(b0 + 8);
    f16x8 h1A = *(const f16x8*)(b1);
    f16x8 l1A = *(const f16x8*)(b1 + 8);

    #pragma unroll 1
    for (int ks = 0; ks < 16; ks += 2) {
      f16x8 h0B = *(const f16x8*)(b0 + (ks + 1) * 32);
      f16x8 l0B = *(const f16x8*)(b0 + (ks + 1) * 32 + 8);
      f16x8 h1B = *(const f16x8*)(b1 + (ks + 1) * 32);
      f16x8 l1B = *(const f16x8*)(b1 + (ks + 1) * 32 + 8);
      {
        f16x8 ah0, ah1, al0, al1;
        AFRAG(ks, ah0, ah1, al0, al1);
        DOMFMA(ah0, ah1, al0, al1, h0A, h1A, l0A, l1A);
      }
      if (ks + 2 < 16) {
        h0A = *(const f16x8*)(b0 + (ks + 2) * 32);
        l0A = *(const f16x8*)(b0 + (ks + 2) * 32 + 8);
        h1A = *(const f16x8*)(b1 + (ks + 2) * 32);
        l1A = *(const f16x8*)(b1 + (ks + 2) * 32 + 8);
      }
      {
        f16x8 ah0, ah1, al0, al1;
        AFRAG(ks + 1, ah0, ah1, al0, al1);
        DOMFMA(ah0, ah1, al0, al1, h0B, h1B, l0B, l1B);
      }
    }

    // ---- per-nc epilogue: wave-local argmax -> global candidates ----
    const int cbase = nc * 256 + wn * 64 + l31;
    #pragma unroll
    for (int mf = 0; mf < 2; ++mf) {
      #pragma unroll
      for (int rg = 0; rg < 16; ++rg) {
        float d0 = acc1[mf][0][rg] + acc2[mf][0][rg] * INV2048;
        float d1 = acc1[mf][1][rg] + acc2[mf][1][rg] * INV2048;
        float dv = d0; int dc = cbase;
        if (d1 > d0) { dv = d1; dc = cbase + 32; }   // tie -> lower col
        #pragma unroll
        for (int off = 1; off < 32; off <<= 1) {
          float ov = __shfl_xor(dv, off);
          int   oc = __shfl_xor(dc, off);
          if (ov > dv || (ov == dv && oc < dc)) { dv = ov; dc = oc; }
        }
        if (l31 == 0) {
          int rloc = wm * 64 + mf * 32 + (rg & 3) + 8 * (rg >> 2) + 4 * half;
          cand[(brow0 + rloc) * 16 + nc * 4 + wn] = make_float2(dv, __int_as_float(dc));
        }
      }
    }
  }
}

// ---------------------------------------------------------------------------
// Kernel 3: merge 16 candidates per row -> bucket + counts
// ---------------------------------------------------------------------------
__global__ __launch_bounds__(256) void merge_kernel(
    const float2* __restrict__ cand, int* __restrict__ buckets, int* __restrict__ counts)
{
  int row = blockIdx.x * 256 + threadIdx.x;
  float bv = -1e30f; int bc = 0;
  #pragma unroll
  for (int s = 0; s < 16; ++s) {
    float2 c = cand[(size_t)row * 16 + s];
    int cc = __float_as_int(c.y);
    if (c.x > bv || (c.x == bv && cc < bc)) { bv = c.x; bc = cc; }
  }
  buckets[row] = bc;
  atomicAdd(&counts[bc], 1);
}

// ---------------------------------------------------------------------------
// Prefix over counts (1 block, 1024 threads)
// ---------------------------------------------------------------------------
__global__ __launch_bounds__(1024) void prefix_kernel(
    const int* __restrict__ counts, int* __restrict__ offsets, int* __restrict__ cursors)
{
  __shared__ int ws[16];
  int tid = threadIdx.x, lane = tid & 63, w = tid >> 6;
  int c = counts[tid];
  int s = c;
  #pragma unroll
  for (int off = 1; off < 64; off <<= 1) {
    int o = __shfl_up(s, off);
    if (lane >= off) s += o;
  }
  if (lane == 63) ws[w] = s;
  __syncthreads();
  if (w == 0 && lane < 16) {
    int t = ws[lane];
    #pragma unroll
    for (int off = 1; off < 16; off <<= 1) {
      int o = __shfl_up(t, off);
      if (lane >= off) t += o;
    }
    ws[lane] = t;
  }
  __syncthreads();
  int base = (w > 0) ? ws[w - 1] : 0;
  int incl = base + s;
  offsets[tid + 1] = incl;
  cursors[tid] = incl - c;
  if (tid == 0) offsets[0] = 0;
}

// ---------------------------------------------------------------------------
// Scatter row ids into per-bucket slots
// ---------------------------------------------------------------------------
__global__ __launch_bounds__(256) void scatter_kernel(
    const int* __restrict__ buckets, int* __restrict__ cursors, int* __restrict__ rowids)
{
  int i = blockIdx.x * 256 + threadIdx.x;
  if (i < M_ROWS) {
    int b = buckets[i];
    int p = atomicAdd(&cursors[b], 1);
    rowids[p] = i;
  }
}

// ---------------------------------------------------------------------------
// Per-bucket gather-reduce + l2norm; empty bucket -> keep normalized mean.
// 1 block per bucket; thread t owns 4 B of the packed row (uint-coalesced).
// tid*4 byte = chunk c=tid>>3, sel=(tid>>2)&1 (0 hi / 1 lo), pos=tid&3.
// ---------------------------------------------------------------------------
__global__ __launch_bounds__(256) void reduce_kernel(
    const f16* __restrict__ xpk, const int* __restrict__ offsets,
    const int* __restrict__ rowids, const f16* __restrict__ mpk,
    float* __restrict__ xglobal)
{
  int t = blockIdx.x, tid = threadIdx.x;
  int beg = offsets[t], end = offsets[t + 1];
  const int sel = (tid >> 2) & 1;
  float a0 = 0.f, a1 = 0.f;
  int o = beg;
  for (; o + 2 <= end; o += 2) {
    int r0 = rowids[o], r1 = rowids[o + 1];
    f16x2 u0 = *(const f16x2*)((const char*)xpk + (size_t)r0 * 1024 + tid * 4);
    f16x2 u1 = *(const f16x2*)((const char*)xpk + (size_t)r1 * 1024 + tid * 4);
    a0 += (float)u0[0] + (float)u1[0];
    a1 += (float)u0[1] + (float)u1[1];
  }
  for (; o < end; ++o) {
    int r = rowids[o];
    f16x2 u = *(const f16x2*)((const char*)xpk + (size_t)r * 1024 + tid * 4);
    a0 += (float)u[0];
    a1 += (float)u[1];
  }
  __shared__ float exch[256][2];
  exch[tid][0] = a0; exch[tid][1] = a1;
  __syncthreads();
  float v0 = 0.f, v1 = 0.f, sq = 0.f;
  if (sel == 0) {
    v0 = a0 + exch[tid + 4][0] * INV2048;
    v1 = a1 + exch[tid + 4][1] * INV2048;
    sq = v0 * v0 + v1 * v1;
  }
  #pragma unroll
  for (int off = 1; off < 64; off <<= 1) sq += __shfl_xor(sq, off);
  __shared__ float wsum[4];
  if ((tid & 63) == 0) wsum[tid >> 6] = sq;
  __syncthreads();
  float tot = wsum[0] + wsum[1] + wsum[2] + wsum[3];
  float rn = 1.0f / fmaxf(sqrtf(tot), 1e-12f);
  if (sel == 0) {
    float o0, o1;
    if (end > beg) { o0 = v0 * rn; o1 = v1 * rn; }
    else {
      f16x2 h = *(const f16x2*)((const char*)mpk + (size_t)t * 1024 + tid * 4);
      f16x2 l = *(const f16x2*)((const char*)mpk + (size_t)t * 1024 + tid * 4 + 16);
      o0 = (float)h[0] + (float)l[0] * INV2048;
      o1 = (float)h[1] + (float)l[1] * INV2048;
    }
    int e = (tid >> 3) * 8 + (tid & 3) * 2;
    *(float2*)&xglobal[(size_t)t * DIM + e] = make_float2(o0, o1);
  }
}

// ---------------------------------------------------------------------------
// k/v projections (fp32 vector; tiny)
// ---------------------------------------------------------------------------
#define TB 8
__global__ __launch_bounds__(256) void kv_kernel(
    const float* __restrict__ xg_in, const float* __restrict__ Wk,
    const float* __restrict__ Wv, float* __restrict__ out)
{
  __shared__ float xg[TB][DIM];     // 8 KB
  __shared__ float Wc[DIM][33];     // 33.8 KB
  int tid = threadIdx.x;
  int t0 = blockIdx.x * TB;
  for (int i = tid; i < TB * DIM; i += 256) xg[i >> 8][i & 255] = xg_in[(size_t)t0 * DIM + i];
  float acck[TB], accv[TB];
  #pragma unroll
  for (int tt = 0; tt < TB; ++tt) { acck[tt] = 0.f; accv[tt] = 0.f; }

  for (int c = 0; c < DIM; c += 32) {
    __syncthreads();
    for (int i = tid; i < DIM * 8; i += 256) {
      int j = i >> 3, d4 = i & 7;
      float4 wv4 = *(const float4*)&Wk[(size_t)j * DIM + c + d4 * 4];
      Wc[j][d4 * 4 + 0] = wv4.x; Wc[j][d4 * 4 + 1] = wv4.y;
      Wc[j][d4 * 4 + 2] = wv4.z; Wc[j][d4 * 4 + 3] = wv4.w;
    }
    __syncthreads();
    #pragma unroll 8
    for (int dd = 0; dd < 32; ++dd) {
      float w = Wc[tid][dd];
      #pragma unroll
      for (int tt = 0; tt < TB; ++tt) acck[tt] = fmaf(w, xg[tt][c + dd], acck[tt]);
    }
  }
  for (int c = 0; c < DIM; c += 32) {
    __syncthreads();
    for (int i = tid; i < DIM * 8; i += 256) {
      int j = i >> 3, d4 = i & 7;
      float4 wv4 = *(const float4*)&Wv[(size_t)j * DIM + c + d4 * 4];
      Wc[j][d4 * 4 + 0] = wv4.x; Wc[j][d4 * 4 + 1] = wv4.y;
      Wc[j][d4 * 4 + 2] = wv4.z; Wc[j][d4 * 4 + 3] = wv4.w;
    }
    __syncthreads();
    #pragma unroll 8
    for (int dd = 0; dd < 32; ++dd) {
      float w = Wc[tid][dd];
      #pragma unroll
      for (int tt = 0; tt < TB; ++tt) accv[tt] = fmaf(w, xg[tt][c + dd], accv[tt]);
    }
  }
  int h = tid >> 5, d = tid & 31;
  #pragma unroll
  for (int tt = 0; tt < TB; ++tt) {
    out[(size_t)h * (T_CL * DH) + (size_t)(t0 + tt) * DH + d] = acck[tt];
    out[262144 + (size_t)h * (T_CL * DH) + (size_t)(t0 + tt) * DH + d] = accv[tt];
  }
}

// ---------------------------------------------------------------------------
extern "C" void kernel_launch(void* const* d_in, const int* in_sizes, int n_in,
                              void* d_out, int out_size, void* d_ws, size_t ws_size,
                              hipStream_t stream)
{
  const float* normed_x = (const float*)d_in[0];   // [8,16384,256]
  const float* x_means  = (const float*)d_in[1];   // [1024,256]
  const float* Wk       = (const float*)d_in[2];   // [256,256]
  const float* Wv       = (const float*)d_in[3];   // [256,256]
  float* out = (float*)d_out;                      // k|v|x_global = 786432 f32

  char* w = (char*)d_ws;
  f16*    xpk     = (f16*)(w);                     // 134217728 B
  f16*    mpk     = (f16*)(w + 134217728);         // 1048576 B
  float2* cand    = (float2*)(w + 135266304);      // 16777216 B
  int*    buckets = (int*)(w + 152043520);         // 524288 B
  int*    counts  = (int*)(w + 152567808);         // 4096 B
  int*    offsets = (int*)(w + 152571904);         // 4352 B
  int*    cursors = (int*)(w + 152576256);         // 4096 B
  int*    rowids  = (int*)(w + 152580352);         // 524288 B (end ~153.1 MB)

  hipMemsetAsync(counts, 0, T_CL * sizeof(int), stream);

  hipLaunchKernelGGL(norm_split_kernel, dim3(T_CL / 4), dim3(256), 0, stream,
                     x_means, mpk, T_CL);
  hipLaunchKernelGGL(norm_split_kernel, dim3(M_ROWS / 4), dim3(256), 0, stream,
                     normed_x, xpk, M_ROWS);
  hipLaunchKernelGGL(dist_argmax_kernel, dim3(M_ROWS / 128), dim3(512), 0, stream,
                     xpk, mpk, cand);
  hipLaunchKernelGGL(merge_kernel, dim3(M_ROWS / 256), dim3(256), 0, stream,
                     cand, buckets, counts);
  hipLaunchKernelGGL(prefix_kernel, dim3(1), dim3(1024), 0, stream,
                     counts, offsets, cursors);
  hipLaunchKernelGGL(scatter_kernel, dim3(M_ROWS / 256), dim3(256), 0, stream,
                     buckets, cursors, rowids);
  hipLaunchKernelGGL(reduce_kernel, dim3(T_CL), dim3(256), 0, stream,
                     xpk, offsets, rowids, mpk, out + 524288);
  hipLaunchKernelGGL(kv_kernel, dim3(T_CL / TB), dim3(256), 0, stream,
                     out + 524288, Wk, Wv, out);
}

// Round 4
// 755.513 us; speedup vs baseline: 1.1499x; 1.0694x over previous
//
#include <hip/hip_runtime.h>

// ---------------- problem constants (fixed by reference) ----------------
#define M_ROWS 131072      // B*N = 8*16384
#define DIM    256
#define T_CL   1024
#define HEADS  8
#define DH     32

typedef _Float16 f16;
typedef _Float16 f16x4 __attribute__((ext_vector_type(4)));
typedef _Float16 f16x8 __attribute__((ext_vector_type(8)));
typedef float    f32x16 __attribute__((ext_vector_type(16)));

#define INV2048 (1.0f/2048.0f)

// Native MFMA layout ("nv"): rows in groups of 32. Per group:
//   f16 offset = ((g*32 + c)*2 + sel)*256 + r31*8 + e
// where c = chunk (8 elems) = 2*ks + half, sel = 0 hi / 1 lo, r31 = row&31.
// Group = 16384 f16 = 32 KB. Fragment loads are fully coalesced.

// ---------------------------------------------------------------------------
// Kernel 1: row L2-normalize, split f16 hi + f16 lo*2048 into native layout,
// and store 1/||row|| for the f32 reduce path. One wave per row.
// ---------------------------------------------------------------------------
__global__ __launch_bounds__(256) void norm_split_kernel(
    const float* __restrict__ src, f16* __restrict__ pk,
    float* __restrict__ rnorm, int nrows)
{
  int lane = threadIdx.x & 63;
  int wid  = threadIdx.x >> 6;
  int row  = blockIdx.x * 4 + wid;
  if (row >= nrows) return;
  const float4 v = *(const float4*)&src[(size_t)row * DIM + lane * 4];
  float ss = v.x*v.x + v.y*v.y + v.z*v.z + v.w*v.w;
  #pragma unroll
  for (int off = 1; off < 64; off <<= 1) ss += __shfl_xor(ss, off);
  float rn = 1.0f / fmaxf(sqrtf(ss), 1e-12f);
  float n0 = v.x*rn, n1 = v.y*rn, n2 = v.z*rn, n3 = v.w*rn;
  f16 h0 = (f16)n0, h1 = (f16)n1, h2 = (f16)n2, h3 = (f16)n3;
  f16 l0 = (f16)((n0 - (float)h0) * 2048.0f);
  f16 l1 = (f16)((n1 - (float)h1) * 2048.0f);
  f16 l2 = (f16)((n2 - (float)h2) * 2048.0f);
  f16 l3 = (f16)((n3 - (float)h3) * 2048.0f);
  f16x4 hv = {h0, h1, h2, h3};
  f16x4 lv = {l0, l1, l2, l3};
  // lane covers elems 4*lane..4*lane+3: chunk c = lane>>1, within-chunk (lane&1)*4
  int g = row >> 5, r31 = row & 31;
  size_t base = ((size_t)(g * 32 + (lane >> 1)) * 2) * 256 + r31 * 8 + (lane & 1) * 4;
  *(f16x4*)(pk + base)       = hv;   // sel=0 (hi)
  *(f16x4*)(pk + base + 256) = lv;   // sel=1 (lo)
  if (lane == 0) rnorm[row] = rn;
}

// ---------------------------------------------------------------------------
// Kernel 2: dists GEMM (f16-split, 3 MFMA passes, 32x32x16) + fused argmax.
// A-stationary: each wave holds 32 rows x K=256 (hi+lo) in 128 VGPRs.
// B streamed global->VGPR from L2/L1 (native layout, coalesced), 4-deep
// prefetch. ZERO LDS. Per-nc barrier keeps 8 waves on the same 32 KB
// B-window for L1 reuse. Argmax carried in registers across all 1024 cols.
// ---------------------------------------------------------------------------
#define MFMA16(A,B,C) __builtin_amdgcn_mfma_f32_32x32x16_f16(A,B,C,0,0,0)

__global__ __launch_bounds__(512, 2) void dist_argmax_kernel(
    const f16* __restrict__ xpk, const f16* __restrict__ mpk,
    int* __restrict__ buckets, int* __restrict__ counts)
{
  const int tid  = threadIdx.x;
  const int lane = tid & 63;
  const int wid  = tid >> 6;          // 0..7
  const int l31  = lane & 31;
  const int half = lane >> 5;
  const int g    = blockIdx.x * 8 + wid;   // row group (32 rows), 4096 total

  // ---- load A fragments for full K=256 (hi+lo), coalesced, once ----
  f16x8 ah[16], al[16];
  const f16* abase = xpk + (size_t)g * 16384 + half * 512 + l31 * 8;
  #pragma unroll
  for (int ks = 0; ks < 16; ++ks) {
    ah[ks] = *(const f16x8*)(abase + ks * 1024);        // c=2ks+half, sel=0
    al[ks] = *(const f16x8*)(abase + ks * 1024 + 256);  // sel=1
  }

  float rbest[16];
  int   rcol[16];
  #pragma unroll
  for (int i = 0; i < 16; ++i) { rbest[i] = -1e30f; rcol[i] = 0; }

  const f16* mbase = mpk + half * 512 + l31 * 8;

  #pragma unroll 1
  for (int nc = 0; nc < 32; ++nc) {
    __syncthreads();   // keep the 8 waves on the same B window (L1 reuse)
    const f16* __restrict__ mb = mbase + (size_t)nc * 16384;

    f16x8 bh[4], bl[4];
    #pragma unroll
    for (int p = 0; p < 4; ++p) {
      bh[p] = *(const f16x8*)(mb + p * 1024);
      bl[p] = *(const f16x8*)(mb + p * 1024 + 256);
    }

    f32x16 acc1, acc2;
    #pragma unroll
    for (int r = 0; r < 16; ++r) { acc1[r] = 0.f; acc2[r] = 0.f; }

    #pragma unroll
    for (int ks = 0; ks < 16; ++ks) {
      const int s = ks & 3;
      acc1 = MFMA16(ah[ks], bh[s], acc1);
      acc2 = MFMA16(ah[ks], bl[s], acc2);
      acc2 = MFMA16(al[ks], bh[s], acc2);
      if (ks < 12) {
        bh[s] = *(const f16x8*)(mb + (ks + 4) * 1024);
        bl[s] = *(const f16x8*)(mb + (ks + 4) * 1024 + 256);
      }
    }

    // ---- fold into running per-lane argmax (col = nc*32 + l31) ----
    const int ccol = nc * 32 + l31;
    #pragma unroll
    for (int rg = 0; rg < 16; ++rg) {
      float d = acc1[rg] + acc2[rg] * INV2048;
      if (d > rbest[rg]) { rbest[rg] = d; rcol[rg] = ccol; }  // strict > : lowest col on tie
    }
  }

  // ---- final reduce across 32 cols held by lanes of same half ----
  #pragma unroll
  for (int rg = 0; rg < 16; ++rg) {
    #pragma unroll
    for (int off = 1; off < 32; off <<= 1) {
      float ov = __shfl_xor(rbest[rg], off);
      int   oc = __shfl_xor(rcol[rg], off);
      if (ov > rbest[rg] || (ov == rbest[rg] && oc < rcol[rg])) {
        rbest[rg] = ov; rcol[rg] = oc;
      }
    }
  }
  if (l31 == 0) {
    #pragma unroll
    for (int rg = 0; rg < 16; ++rg) {
      int rloc = (rg & 3) + 8 * (rg >> 2) + 4 * half;
      int grow = g * 32 + rloc;
      buckets[grow] = rcol[rg];
      atomicAdd(&counts[rcol[rg]], 1);
    }
  }
}

// ---------------------------------------------------------------------------
// Prefix over counts (1 block, 1024 threads)
// ---------------------------------------------------------------------------
__global__ __launch_bounds__(1024) void prefix_kernel(
    const int* __restrict__ counts, int* __restrict__ offsets, int* __restrict__ cursors)
{
  __shared__ int ws[16];
  int tid = threadIdx.x, lane = tid & 63, w = tid >> 6;
  int c = counts[tid];
  int s = c;
  #pragma unroll
  for (int off = 1; off < 64; off <<= 1) {
    int o = __shfl_up(s, off);
    if (lane >= off) s += o;
  }
  if (lane == 63) ws[w] = s;
  __syncthreads();
  if (w == 0 && lane < 16) {
    int t = ws[lane];
    #pragma unroll
    for (int off = 1; off < 16; off <<= 1) {
      int o = __shfl_up(t, off);
      if (lane >= off) t += o;
    }
    ws[lane] = t;
  }
  __syncthreads();
  int base = (w > 0) ? ws[w - 1] : 0;
  int incl = base + s;
  offsets[tid + 1] = incl;
  cursors[tid] = incl - c;
  if (tid == 0) offsets[0] = 0;
}

// ---------------------------------------------------------------------------
// Scatter row ids into per-bucket slots
// ---------------------------------------------------------------------------
__global__ __launch_bounds__(256) void scatter_kernel(
    const int* __restrict__ buckets, int* __restrict__ cursors, int* __restrict__ rowids)
{
  int i = blockIdx.x * 256 + threadIdx.x;
  if (i < M_ROWS) {
    int b = buckets[i];
    int p = atomicAdd(&cursors[b], 1);
    rowids[p] = i;
  }
}

// ---------------------------------------------------------------------------
// Per-bucket gather-reduce (f32 path: original input x stored row norms)
// + l2norm; empty bucket -> normalized mean. 1 block/bucket, thread = dim.
// ---------------------------------------------------------------------------
__global__ __launch_bounds__(256) void reduce_kernel(
    const float* __restrict__ xraw, const float* __restrict__ rnx,
    const int* __restrict__ offsets, const int* __restrict__ rowids,
    const float* __restrict__ mraw, const float* __restrict__ rnm,
    float* __restrict__ xglobal)
{
  int t = blockIdx.x, tid = threadIdx.x;
  int beg = offsets[t], end = offsets[t + 1];
  float acc = 0.f;
  for (int o = beg; o < end; ++o) {
    int r = rowids[o];
    acc += xraw[(size_t)r * DIM + tid] * rnx[r];
  }
  float sq = acc * acc;
  #pragma unroll
  for (int off = 1; off < 64; off <<= 1) sq += __shfl_xor(sq, off);
  __shared__ float wsum[4];
  if ((tid & 63) == 0) wsum[tid >> 6] = sq;
  __syncthreads();
  float tot = wsum[0] + wsum[1] + wsum[2] + wsum[3];
  float rn = 1.0f / fmaxf(sqrtf(tot), 1e-12f);
  float outv;
  if (end > beg) outv = acc * rn;
  else outv = mraw[(size_t)t * DIM + tid] * rnm[t];
  xglobal[(size_t)t * DIM + tid] = outv;
}

// ---------------------------------------------------------------------------
// k/v projections (fp32 vector; tiny)
// ---------------------------------------------------------------------------
#define TB 8
__global__ __launch_bounds__(256) void kv_kernel(
    const float* __restrict__ xg_in, const float* __restrict__ Wk,
    const float* __restrict__ Wv, float* __restrict__ out)
{
  __shared__ float xg[TB][DIM];     // 8 KB
  __shared__ float Wc[DIM][33];     // 33.8 KB
  int tid = threadIdx.x;
  int t0 = blockIdx.x * TB;
  for (int i = tid; i < TB * DIM; i += 256) xg[i >> 8][i & 255] = xg_in[(size_t)t0 * DIM + i];
  float acck[TB], accv[TB];
  #pragma unroll
  for (int tt = 0; tt < TB; ++tt) { acck[tt] = 0.f; accv[tt] = 0.f; }

  for (int c = 0; c < DIM; c += 32) {
    __syncthreads();
    for (int i = tid; i < DIM * 8; i += 256) {
      int j = i >> 3, d4 = i & 7;
      float4 wv4 = *(const float4*)&Wk[(size_t)j * DIM + c + d4 * 4];
      Wc[j][d4 * 4 + 0] = wv4.x; Wc[j][d4 * 4 + 1] = wv4.y;
      Wc[j][d4 * 4 + 2] = wv4.z; Wc[j][d4 * 4 + 3] = wv4.w;
    }
    __syncthreads();
    #pragma unroll 8
    for (int dd = 0; dd < 32; ++dd) {
      float w = Wc[tid][dd];
      #pragma unroll
      for (int tt = 0; tt < TB; ++tt) acck[tt] = fmaf(w, xg[tt][c + dd], acck[tt]);
    }
  }
  for (int c = 0; c < DIM; c += 32) {
    __syncthreads();
    for (int i = tid; i < DIM * 8; i += 256) {
      int j = i >> 3, d4 = i & 7;
      float4 wv4 = *(const float4*)&Wv[(size_t)j * DIM + c + d4 * 4];
      Wc[j][d4 * 4 + 0] = wv4.x; Wc[j][d4 * 4 + 1] = wv4.y;
      Wc[j][d4 * 4 + 2] = wv4.z; Wc[j][d4 * 4 + 3] = wv4.w;
    }
    __syncthreads();
    #pragma unroll 8
    for (int dd = 0; dd < 32; ++dd) {
      float w = Wc[tid][dd];
      #pragma unroll
      for (int tt = 0; tt < TB; ++tt) accv[tt] = fmaf(w, xg[tt][c + dd], accv[tt]);
    }
  }
  int h = tid >> 5, d = tid & 31;
  #pragma unroll
  for (int tt = 0; tt < TB; ++tt) {
    out[(size_t)h * (T_CL * DH) + (size_t)(t0 + tt) * DH + d] = acck[tt];
    out[262144 + (size_t)h * (T_CL * DH) + (size_t)(t0 + tt) * DH + d] = accv[tt];
  }
}

// ---------------------------------------------------------------------------
extern "C" void kernel_launch(void* const* d_in, const int* in_sizes, int n_in,
                              void* d_out, int out_size, void* d_ws, size_t ws_size,
                              hipStream_t stream)
{
  const float* normed_x = (const float*)d_in[0];   // [8,16384,256]
  const float* x_means  = (const float*)d_in[1];   // [1024,256]
  const float* Wk       = (const float*)d_in[2];   // [256,256]
  const float* Wv       = (const float*)d_in[3];   // [256,256]
  float* out = (float*)d_out;                      // k|v|x_global = 786432 f32

  char* w = (char*)d_ws;
  f16*   xpk     = (f16*)(w);                      // 134217728 B
  f16*   mpk     = (f16*)(w + 134217728);          // 1048576 B
  float* rnx     = (float*)(w + 135266304);        // 524288 B
  float* rnm     = (float*)(w + 135790592);        // 4096 B
  int*   buckets = (int*)(w + 135794688);          // 524288 B
  int*   counts  = (int*)(w + 136318976);          // 4096 B
  int*   offsets = (int*)(w + 136323072);          // 4352 B
  int*   cursors = (int*)(w + 136327424);          // 4096 B
  int*   rowids  = (int*)(w + 136331520);          // 524288 B (end ~136.9 MB)

  hipMemsetAsync(counts, 0, T_CL * sizeof(int), stream);

  hipLaunchKernelGGL(norm_split_kernel, dim3(T_CL / 4), dim3(256), 0, stream,
                     x_means, mpk, rnm, T_CL);
  hipLaunchKernelGGL(norm_split_kernel, dim3(M_ROWS / 4), dim3(256), 0, stream,
                     normed_x, xpk, rnx, M_ROWS);
  hipLaunchKernelGGL(dist_argmax_kernel, dim3(M_ROWS / 256), dim3(512), 0, stream,
                     xpk, mpk, buckets, counts);
  hipLaunchKernelGGL(prefix_kernel, dim3(1), dim3(1024), 0, stream,
                     counts, offsets, cursors);
  hipLaunchKernelGGL(scatter_kernel, dim3(M_ROWS / 256), dim3(256), 0, stream,
                     buckets, cursors, rowids);
  hipLaunchKernelGGL(reduce_kernel, dim3(T_CL), dim3(256), 0, stream,
                     normed_x, rnx, offsets, rowids, x_means, rnm, out + 524288);
  hipLaunchKernelGGL(kv_kernel, dim3(T_CL / TB), dim3(256), 0, stream,
                     out + 524288, Wk, Wv, out);
}

// Round 5
// 577.501 us; speedup vs baseline: 1.5044x; 1.3082x over previous
//
#include <hip/hip_runtime.h>

// ---------------- problem constants (fixed by reference) ----------------
#define M_ROWS 131072      // B*N = 8*16384
#define DIM    256
#define T_CL   1024
#define HEADS  8
#define DH     32

typedef _Float16 f16;
typedef _Float16 f16x4 __attribute__((ext_vector_type(4)));
typedef _Float16 f16x8 __attribute__((ext_vector_type(8)));
typedef float    f32x16 __attribute__((ext_vector_type(16)));

#define INV2048 (1.0f/2048.0f)

// Native MFMA layout ("nv"): rows in groups of 32. Per group (32 KB):
//   byte offset = c*1024 + sel*512 + r31*16 + e*2
// where c = chunk of 8 elems (c = 2*ks + half), sel = 0 hi / 1 lo,
// r31 = row&31, e = elem within chunk. Fragment loads are coalesced
// (lane l31 -> r31*16, 16 B each, contiguous 512 B per 32-lane half).

// ---------------------------------------------------------------------------
// Kernel 1: group-wise L2-normalize + hi/lo split into native layout.
// Block = 512 thr = one 32-row group. Scattered native-layout writes go to
// swizzled LDS; LDS->global copy is fully coalesced (16 B/lane).
// Swizzle: byte ^= ((byte>>10)&7)<<4  (involution; c[2:0] -> bank bits).
// ---------------------------------------------------------------------------
#define SWZ(b) ((b) ^ ((((b) >> 10) & 7) << 4))

__global__ __launch_bounds__(512) void norm_split_kernel(
    const float* __restrict__ src, f16* __restrict__ pk,
    float* __restrict__ rnorm)
{
  __shared__ alignas(16) char buf[32768];
  const int tid  = threadIdx.x;
  const int lane = tid & 63;
  const int w    = tid >> 6;
  const int g    = blockIdx.x;

  #pragma unroll
  for (int j = 0; j < 4; ++j) {
    int r31 = w * 4 + j;
    int row = g * 32 + r31;
    const float4 v = *(const float4*)&src[(size_t)row * DIM + lane * 4];
    float ss = v.x*v.x + v.y*v.y + v.z*v.z + v.w*v.w;
    #pragma unroll
    for (int off = 1; off < 64; off <<= 1) ss += __shfl_xor(ss, off);
    float rn = 1.0f / fmaxf(sqrtf(ss), 1e-12f);
    float n0 = v.x*rn, n1 = v.y*rn, n2 = v.z*rn, n3 = v.w*rn;
    f16 h0 = (f16)n0, h1 = (f16)n1, h2 = (f16)n2, h3 = (f16)n3;
    f16x4 hv = {h0, h1, h2, h3};
    f16x4 lv = {(f16)((n0 - (float)h0) * 2048.0f),
                (f16)((n1 - (float)h1) * 2048.0f),
                (f16)((n2 - (float)h2) * 2048.0f),
                (f16)((n3 - (float)h3) * 2048.0f)};
    // elems 4*lane..+3: chunk c = lane>>1, within-chunk byte (lane&1)*8
    int b  = (lane >> 1) * 1024 + r31 * 16 + (lane & 1) * 8;   // sel=0
    int bl = b + 512;                                          // sel=1
    *(f16x4*)(buf + SWZ(b))  = hv;
    *(f16x4*)(buf + SWZ(bl)) = lv;
    if (lane == 0) rnorm[row] = rn;
  }
  __syncthreads();
  char* gout = (char*)pk + (size_t)g * 32768;
  #pragma unroll
  for (int s = 0; s < 4; ++s) {
    int L = s * 8192 + tid * 16;
    *(float4*)(gout + L) = *(const float4*)(buf + SWZ(L));
  }
}

// ---------------------------------------------------------------------------
// Kernel 2: dists GEMM (f16-split, 3 MFMA passes, 32x32x16) + fused argmax.
// A: 32 rows x K=256 (hi+lo) resident in 128 VGPRs, pinned via opaque asm
//    (prevents the round-4 rematerialization, VGPR_Count was 124 < 128).
// B: staged through LDS double-buffer (32 KB/nc) via global_load_lds;
//    frag reads contiguous per 32-lane half -> conflict-free.
// 2-phase pipeline: issue stage(nc+1), compute(nc), one barrier per nc.
// ---------------------------------------------------------------------------
#define MFMA16(A,B,C) __builtin_amdgcn_mfma_f32_32x32x16_f16(A,B,C,0,0,0)

__global__ __launch_bounds__(512, 2) void dist_argmax_kernel(
    const f16* __restrict__ xpk, const f16* __restrict__ mpk,
    int* __restrict__ buckets, int* __restrict__ counts)
{
  __shared__ alignas(16) char ldsB[2][32768];

  const int tid  = threadIdx.x;
  const int lane = tid & 63;
  const int wid  = tid >> 6;          // 0..7 (row-group within block)
  const int l31  = lane & 31;
  const int half = lane >> 5;
  const int g    = blockIdx.x * 8 + wid;   // row group (32 rows), 4096 total

  // ---- load A fragments for full K=256 (hi+lo), coalesced, ONCE ----
  f16x8 ah[16], al[16];
  const f16* abase = xpk + (size_t)g * 16384 + half * 512 + l31 * 8;
  #pragma unroll
  for (int ks = 0; ks < 16; ++ks) {
    ah[ks] = *(const f16x8*)(abase + ks * 1024);        // c=2ks+half, hi
    al[ks] = *(const f16x8*)(abase + ks * 1024 + 256);  // lo
  }
  // pin: opaque defs the compiler cannot rematerialize from memory
  #pragma unroll
  for (int ks = 0; ks < 16; ++ks)
    asm volatile("" : "+v"(ah[ks]), "+v"(al[ks]));

  const char* mbyte = (const char*)mpk;
#define STAGEB(NC, BUF) { \
    _Pragma("unroll") \
    for (int s = 0; s < 4; ++s) { \
      __builtin_amdgcn_global_load_lds( \
        (const __attribute__((address_space(1))) void*)(mbyte + (size_t)(NC) * 32768 + s * 8192 + tid * 16), \
        (__attribute__((address_space(3))) void*)(&ldsB[BUF][s * 8192 + wid * 1024]), 16, 0, 0); \
    } }

  float rbest[16];
  int   rcol[16];
  #pragma unroll
  for (int i = 0; i < 16; ++i) { rbest[i] = -1e30f; rcol[i] = 0; }

  STAGEB(0, 0);
  __syncthreads();

  #pragma unroll 1
  for (int nc = 0; nc < 32; ++nc) {
    const int buf = nc & 1;
    if (nc < 31) STAGEB(nc + 1, buf ^ 1);

    const char* Bb = ldsB[buf] + half * 1024 + l31 * 16;
    f32x16 acc1, acc2;
    #pragma unroll
    for (int r = 0; r < 16; ++r) { acc1[r] = 0.f; acc2[r] = 0.f; }

    #pragma unroll
    for (int ks = 0; ks < 16; ++ks) {
      f16x8 bh = *(const f16x8*)(Bb + ks * 2048);
      f16x8 bl = *(const f16x8*)(Bb + ks * 2048 + 512);
      acc1 = MFMA16(ah[ks], bh, acc1);
      acc2 = MFMA16(ah[ks], bl, acc2);
      acc2 = MFMA16(al[ks], bh, acc2);
    }

    // ---- fold into running per-lane argmax (col = nc*32 + l31) ----
    const int ccol = nc * 32 + l31;
    #pragma unroll
    for (int rg = 0; rg < 16; ++rg) {
      float d = acc1[rg] + acc2[rg] * INV2048;
      if (d > rbest[rg]) { rbest[rg] = d; rcol[rg] = ccol; }  // strict >: lowest col on tie
    }
    __syncthreads();
  }
#undef STAGEB

  // ---- final reduce across the 32 cols held by lanes of same half ----
  #pragma unroll
  for (int rg = 0; rg < 16; ++rg) {
    #pragma unroll
    for (int off = 1; off < 32; off <<= 1) {
      float ov = __shfl_xor(rbest[rg], off);
      int   oc = __shfl_xor(rcol[rg], off);
      if (ov > rbest[rg] || (ov == rbest[rg] && oc < rcol[rg])) {
        rbest[rg] = ov; rcol[rg] = oc;
      }
    }
  }
  if (l31 == 0) {
    #pragma unroll
    for (int rg = 0; rg < 16; ++rg) {
      int rloc = (rg & 3) + 8 * (rg >> 2) + 4 * half;
      int grow = g * 32 + rloc;
      buckets[grow] = rcol[rg];
      atomicAdd(&counts[rcol[rg]], 1);
    }
  }
}

// ---------------------------------------------------------------------------
// Prefix over counts (1 block, 1024 threads)
// ---------------------------------------------------------------------------
__global__ __launch_bounds__(1024) void prefix_kernel(
    const int* __restrict__ counts, int* __restrict__ offsets, int* __restrict__ cursors)
{
  __shared__ int ws[16];
  int tid = threadIdx.x, lane = tid & 63, w = tid >> 6;
  int c = counts[tid];
  int s = c;
  #pragma unroll
  for (int off = 1; off < 64; off <<= 1) {
    int o = __shfl_up(s, off);
    if (lane >= off) s += o;
  }
  if (lane == 63) ws[w] = s;
  __syncthreads();
  if (w == 0 && lane < 16) {
    int t = ws[lane];
    #pragma unroll
    for (int off = 1; off < 16; off <<= 1) {
      int o = __shfl_up(t, off);
      if (lane >= off) t += o;
    }
    ws[lane] = t;
  }
  __syncthreads();
  int base = (w > 0) ? ws[w - 1] : 0;
  int incl = base + s;
  offsets[tid + 1] = incl;
  cursors[tid] = incl - c;
  if (tid == 0) offsets[0] = 0;
}

// ---------------------------------------------------------------------------
// Scatter row ids into per-bucket slots
// ---------------------------------------------------------------------------
__global__ __launch_bounds__(256) void scatter_kernel(
    const int* __restrict__ buckets, int* __restrict__ cursors, int* __restrict__ rowids)
{
  int i = blockIdx.x * 256 + threadIdx.x;
  if (i < M_ROWS) {
    int b = buckets[i];
    int p = atomicAdd(&cursors[b], 1);
    rowids[p] = i;
  }
}

// ---------------------------------------------------------------------------
// Per-bucket gather-reduce (f32: original input x stored row norms)
// + l2norm; empty bucket -> normalized mean. 1 block/bucket, thread = dim.
// ---------------------------------------------------------------------------
__global__ __launch_bounds__(256) void reduce_kernel(
    const float* __restrict__ xraw, const float* __restrict__ rnx,
    const int* __restrict__ offsets, const int* __restrict__ rowids,
    const float* __restrict__ mraw, const float* __restrict__ rnm,
    float* __restrict__ xglobal)
{
  int t = blockIdx.x, tid = threadIdx.x;
  int beg = offsets[t], end = offsets[t + 1];
  float acc = 0.f;
  for (int o = beg; o < end; ++o) {
    int r = rowids[o];
    acc += xraw[(size_t)r * DIM + tid] * rnx[r];
  }
  float sq = acc * acc;
  #pragma unroll
  for (int off = 1; off < 64; off <<= 1) sq += __shfl_xor(sq, off);
  __shared__ float wsum[4];
  if ((tid & 63) == 0) wsum[tid >> 6] = sq;
  __syncthreads();
  float tot = wsum[0] + wsum[1] + wsum[2] + wsum[3];
  float rn = 1.0f / fmaxf(sqrtf(tot), 1e-12f);
  float outv;
  if (end > beg) outv = acc * rn;
  else outv = mraw[(size_t)t * DIM + tid] * rnm[t];
  xglobal[(size_t)t * DIM + tid] = outv;
}

// ---------------------------------------------------------------------------
// k/v projections (fp32 vector; tiny)
// ---------------------------------------------------------------------------
#define TB 8
__global__ __launch_bounds__(256) void kv_kernel(
    const float* __restrict__ xg_in, const float* __restrict__ Wk,
    const float* __restrict__ Wv, float* __restrict__ out)
{
  __shared__ float xg[TB][DIM];     // 8 KB
  __shared__ float Wc[DIM][33];     // 33.8 KB
  int tid = threadIdx.x;
  int t0 = blockIdx.x * TB;
  for (int i = tid; i < TB * DIM; i += 256) xg[i >> 8][i & 255] = xg_in[(size_t)t0 * DIM + i];
  float acck[TB], accv[TB];
  #pragma unroll
  for (int tt = 0; tt < TB; ++tt) { acck[tt] = 0.f; accv[tt] = 0.f; }

  for (int c = 0; c < DIM; c += 32) {
    __syncthreads();
    for (int i = tid; i < DIM * 8; i += 256) {
      int j = i >> 3, d4 = i & 7;
      float4 wv4 = *(const float4*)&Wk[(size_t)j * DIM + c + d4 * 4];
      Wc[j][d4 * 4 + 0] = wv4.x; Wc[j][d4 * 4 + 1] = wv4.y;
      Wc[j][d4 * 4 + 2] = wv4.z; Wc[j][d4 * 4 + 3] = wv4.w;
    }
    __syncthreads();
    #pragma unroll 8
    for (int dd = 0; dd < 32; ++dd) {
      float w = Wc[tid][dd];
      #pragma unroll
      for (int tt = 0; tt < TB; ++tt) acck[tt] = fmaf(w, xg[tt][c + dd], acck[tt]);
    }
  }
  for (int c = 0; c < DIM; c += 32) {
    __syncthreads();
    for (int i = tid; i < DIM * 8; i += 256) {
      int j = i >> 3, d4 = i & 7;
      float4 wv4 = *(const float4*)&Wv[(size_t)j * DIM + c + d4 * 4];
      Wc[j][d4 * 4 + 0] = wv4.x; Wc[j][d4 * 4 + 1] = wv4.y;
      Wc[j][d4 * 4 + 2] = wv4.z; Wc[j][d4 * 4 + 3] = wv4.w;
    }
    __syncthreads();
    #pragma unroll 8
    for (int dd = 0; dd < 32; ++dd) {
      float w = Wc[tid][dd];
      #pragma unroll
      for (int tt = 0; tt < TB; ++tt) accv[tt] = fmaf(w, xg[tt][c + dd], accv[tt]);
    }
  }
  int h = tid >> 5, d = tid & 31;
  #pragma unroll
  for (int tt = 0; tt < TB; ++tt) {
    out[(size_t)h * (T_CL * DH) + (size_t)(t0 + tt) * DH + d] = acck[tt];
    out[262144 + (size_t)h * (T_CL * DH) + (size_t)(t0 + tt) * DH + d] = accv[tt];
  }
}

// ---------------------------------------------------------------------------
extern "C" void kernel_launch(void* const* d_in, const int* in_sizes, int n_in,
                              void* d_out, int out_size, void* d_ws, size_t ws_size,
                              hipStream_t stream)
{
  const float* normed_x = (const float*)d_in[0];   // [8,16384,256]
  const float* x_means  = (const float*)d_in[1];   // [1024,256]
  const float* Wk       = (const float*)d_in[2];   // [256,256]
  const float* Wv       = (const float*)d_in[3];   // [256,256]
  float* out = (float*)d_out;                      // k|v|x_global = 786432 f32

  char* w = (char*)d_ws;
  f16*   xpk     = (f16*)(w);                      // 134217728 B
  f16*   mpk     = (f16*)(w + 134217728);          // 1048576 B
  float* rnx     = (float*)(w + 135266304);        // 524288 B
  float* rnm     = (float*)(w + 135790592);        // 4096 B
  int*   buckets = (int*)(w + 135794688);          // 524288 B
  int*   counts  = (int*)(w + 136318976);          // 4096 B
  int*   offsets = (int*)(w + 136323072);          // 4352 B
  int*   cursors = (int*)(w + 136327424);          // 4096 B
  int*   rowids  = (int*)(w + 136331520);          // 524288 B (end ~136.9 MB)

  hipMemsetAsync(counts, 0, T_CL * sizeof(int), stream);

  hipLaunchKernelGGL(norm_split_kernel, dim3(T_CL / 32), dim3(512), 0, stream,
                     x_means, mpk, rnm);
  hipLaunchKernelGGL(norm_split_kernel, dim3(M_ROWS / 32), dim3(512), 0, stream,
                     normed_x, xpk, rnx);
  hipLaunchKernelGGL(dist_argmax_kernel, dim3(M_ROWS / 256), dim3(512), 0, stream,
                     xpk, mpk, buckets, counts);
  hipLaunchKernelGGL(prefix_kernel, dim3(1), dim3(1024), 0, stream,
                     counts, offsets, cursors);
  hipLaunchKernelGGL(scatter_kernel, dim3(M_ROWS / 256), dim3(256), 0, stream,
                     buckets, cursors, rowids);
  hipLaunchKernelGGL(reduce_kernel, dim3(T_CL), dim3(256), 0, stream,
                     normed_x, rnx, offsets, rowids, x_means, rnm, out + 524288);
  hipLaunchKernelGGL(kv_kernel, dim3(T_CL / TB), dim3(256), 0, stream,
                     out + 524288, Wk, Wv, out);
}